// Round 13
// baseline (198.598 us; speedup 1.0000x reference)
//
#include <hip/hip_runtime.h>
#include <hip/hip_bf16.h>
#include <stdint.h>

#define DEVINL __device__ __forceinline__

typedef __attribute__((ext_vector_type(4))) float f32x4;
typedef __attribute__((ext_vector_type(8))) __bf16 bfv8;
typedef __attribute__((ext_vector_type(8))) short s16x8;
typedef __attribute__((ext_vector_type(4))) short s16x4;

// ---- helpers ----
DEVINL short f2bf(float f) {  // fp32 -> bf16 bits, RTNE
  union { float f; unsigned u; } v; v.f = f;
  unsigned r = v.u + 0x7FFFu + ((v.u >> 16) & 1u);
  return (short)(r >> 16);
}
DEVINL float bf2f(short h) {
  union { unsigned u; float f; } v; v.u = ((unsigned)(unsigned short)h) << 16;
  return v.f;
}
DEVINL void gload_lds16(const void* g, void* l) {
  // 16B direct global->LDS. LDS dest = wave-uniform base + lane*16.
  __builtin_amdgcn_global_load_lds((__attribute__((address_space(1))) unsigned*)(g),
                                   (__attribute__((address_space(3))) unsigned*)(l),
                                   16, 0, 0);
}
template <int N> DEVINL void vmwaitc() {
  asm volatile("s_waitcnt vmcnt(%0)" :: "i"(N) : "memory");
}
// bijective XCD swizzle (n % 8 == 0): consecutive output slots cluster per XCD
DEVINL int xswz(int p, int n) { return (p & 7) * (n >> 3) + (p >> 3); }

// ========== m97-class core: 128x128 tile, BK=32, 256 threads, 16 KB LDS ==========
// 4 waves (2M x 2N); wave tile 64x64; acc[4][4] of 16x16x32 frags.
// LDS: single buffer A[128][32] @0 (8 KB) + B[128][32] @4096 shorts (8 KB) = 16 KB
// -> ~3 blocks/CU co-resident: INTER-BLOCK wave overlap hides the barrier/latency
// stalls (m114/m97 mechanism) that intra-block scheduling (r6-r12) could not.
// Per K-step: 4 gload_lds(16B)/wave -> vmcnt(0)+bar -> 8 swizzled ds_read_b128 ->
// 16 MFMA -> bar (reads retired before MFMA via compiler lgkm; safe to overwrite).
// Swizzle (64B rows, 4 chunks): storage chunk = logical ^ ((row>>1)&3), applied as
// inverse-swizzled GLOBAL source + swizzled ds_read. Verified 0 conflicts (r2/r6).
DEVINL void gemm97_core(const short* __restrict__ Ag, const short* __restrict__ Bg,
                        int lda, int ldb, int m0, int n0, int nkt,
                        short* lds, f32x4 (&acc)[4][4]) {
  const int tid = threadIdx.x;
  const int w = tid >> 6, l = tid & 63;
  const int wm = w >> 1, wn = w & 1;
  const int lr = l & 15, lg = l >> 4;
  const int ck = ((lg ^ ((lr >> 1) & 3)) << 3);        // swizzled read chunk
  const int aro = (wm * 64 + lr) * 32 + ck;            // + mf*512
  const int bro = 4096 + (wn * 64 + lr) * 32 + ck;     // + nf*512
  const int srow = l >> 2;                             // staging row within 16-row unit
  const int scol = (((l & 3) ^ ((l >> 3) & 3)) << 3);  // inverse-swizzled source col

#pragma unroll 1
  for (int kt = 0; kt < nkt; ++kt) {
    // ---- stage tile kt (A: rows w*32..w*32+31 in 2 gloads; same for B) ----
#pragma unroll
    for (int i = 0; i < 2; ++i) {
      gload_lds16(Ag + (size_t)(m0 + w * 32 + i * 16 + srow) * lda + kt * 32 + scol,
                  lds + w * 1024 + i * 512);
      gload_lds16(Bg + (size_t)(n0 + w * 32 + i * 16 + srow) * ldb + kt * 32 + scol,
                  lds + 4096 + w * 1024 + i * 512);
    }
    vmwaitc<0>();
    __syncthreads();
    // ---- fragments + MFMA ----
    bfv8 af[4], bfr[4];
#pragma unroll
    for (int mf = 0; mf < 4; ++mf) af[mf] = *(const bfv8*)(lds + aro + mf * 512);
#pragma unroll
    for (int nf = 0; nf < 4; ++nf) bfr[nf] = *(const bfv8*)(lds + bro + nf * 512);
#pragma unroll
    for (int mf = 0; mf < 4; ++mf)
#pragma unroll
      for (int nf = 0; nf < 4; ++nf)
        acc[mf][nf] = __builtin_amdgcn_mfma_f32_16x16x32_bf16(af[mf], bfr[nf], acc[mf][nf], 0, 0, 0);
    __syncthreads();  // all waves' reads retired -> next stage may overwrite
  }
}

// ============ prep: cast fp32->bf16 (Q,V) fused with W transpose+cast ============
__global__ __launch_bounds__(256) void prep_kernel(
    const float* __restrict__ q, const float* __restrict__ v,
    const float* __restrict__ Wq, const float* __restrict__ Wk, const float* __restrict__ Wv,
    short* __restrict__ Qc, short* __restrict__ Vc,
    short* __restrict__ WTq, short* __restrict__ WTk, short* __restrict__ WTv) {
  __shared__ float tile[64][65];
  const int bx = blockIdx.x;
  if (bx < 8192) {
    const float* src = (bx < 4096) ? q : v;
    short* dst = (bx < 4096) ? Qc : Vc;
    const size_t i = ((size_t)(bx & 4095) * 256 + threadIdx.x) * 8;
    f32x4 x0 = *(const f32x4*)(src + i);
    f32x4 x1 = *(const f32x4*)(src + i + 4);
    s16x8 o;
#pragma unroll
    for (int j = 0; j < 4; ++j) { o[j] = f2bf(x0[j]); o[4 + j] = f2bf(x1[j]); }
    *(s16x8*)(dst + i) = o;
  } else {
    const int z = (bx - 8192) >> 8, xx = (bx - 8192) & 255;
    const float* W = (z == 0) ? Wq : (z == 1) ? Wk : Wv;
    short* WT = (z == 0) ? WTq : (z == 1) ? WTk : WTv;
    const int k0 = (xx & 15) << 6, n0 = (xx >> 4) << 6;
    const int c = threadIdx.x & 63, r0 = threadIdx.x >> 6;
#pragma unroll
    for (int i = 0; i < 16; ++i) {
      int r = (i << 2) + r0;
      tile[r][c] = W[(size_t)(k0 + r) * 1024 + n0 + c];
    }
    __syncthreads();
#pragma unroll
    for (int i = 0; i < 16; ++i) {
      int a = (i << 2) + r0;
      WT[(size_t)(n0 + a) * 1024 + k0 + c] = f2bf(tile[c][a]);
    }
  }
}

// ==== Q+K projections: 128x128 tile, grid 1024 (2 sel x 64 bm x 8 bn), ~3 blk/CU ====
__global__ __launch_bounds__(256, 3) void qkproj_kernel(
    const short* __restrict__ Qc, const short* __restrict__ Vc,
    const short* __restrict__ WTq, const short* __restrict__ WTk,
    const float* __restrict__ bq, const float* __restrict__ bk,
    short* __restrict__ Qb, short* __restrict__ Kb) {
  __shared__ short lds[8192];  // 16 KB
  const int o = xswz(blockIdx.x, 1024);
  const int sel = o >> 9, r = o & 511;
  const int bm = r >> 3, bn = r & 7;          // bm:[0,64) bn:[0,8)
  const short* A = sel ? Vc : Qc;
  const short* BT = sel ? WTk : WTq;
  const float* bias = sel ? bk : bq;
  short* O = sel ? Kb : Qb;
  const int m0 = bm * 128, n0 = bn * 128;
  f32x4 acc[4][4];
#pragma unroll
  for (int i = 0; i < 4; ++i)
#pragma unroll
    for (int j = 0; j < 4; ++j) acc[i][j] = (f32x4){0.f, 0.f, 0.f, 0.f};
  gemm97_core(A, BT, 1024, 1024, m0, n0, 32, lds, acc);
  const int l = threadIdx.x & 63, w = threadIdx.x >> 6;
  const int wm = w >> 1, wn = w & 1, lr = l & 15, lg = l >> 4;
#pragma unroll
  for (int mf = 0; mf < 4; ++mf) {
    const int row0 = m0 + wm * 64 + mf * 16 + lg * 4;  // <= 8191
#pragma unroll
    for (int nf = 0; nf < 4; ++nf) {
      const int col = n0 + wn * 64 + nf * 16 + lr;     // <= 1023
      const float bb = bias[col];
#pragma unroll
      for (int j = 0; j < 4; ++j)
        O[(size_t)(row0 + j) * 1024 + col] = f2bf(acc[mf][nf][j] + bb);
    }
  }
}

// ==== V projection -> VT[b][u][t]: 128x128 tile, grid 512 (64 bm x 8 bn) ====
// Epilogue: two-pass LDS transpose (buf [64][136], 17 KB) -> coalesced s16x8 stores.
__global__ __launch_bounds__(256, 3) void vproj_kernel(
    const short* __restrict__ Vc, const short* __restrict__ WTv,
    const float* __restrict__ bv, short* __restrict__ VT) {
  __shared__ short lds[8704];  // core uses [0,8192); transpose buf [64][136] = 8704
  const int o = xswz(blockIdx.x, 512);
  const int bm = o >> 3, bn = o & 7;          // bm:[0,64) bn:[0,8)
  const int m0 = bm * 128, n0 = bn * 128;     // m = t rows, n = u cols
  f32x4 acc[4][4];
#pragma unroll
  for (int i = 0; i < 4; ++i)
#pragma unroll
    for (int j = 0; j < 4; ++j) acc[i][j] = (f32x4){0.f, 0.f, 0.f, 0.f};
  gemm97_core(Vc, WTv, 1024, 1024, m0, n0, 32, lds, acc);
  const int tid = threadIdx.x;
  const int l = tid & 63, w = tid >> 6;
  const int wm = w >> 1, wn = w & 1, lr = l & 15, lg = l >> 4;
  const int b = m0 >> 11, t0 = m0 & 2047;
#pragma unroll 1
  for (int h = 0; h < 2; ++h) {  // u-halves: waves with wn==h hold these columns
    if (wn == h) {
#pragma unroll
      for (int mf = 0; mf < 4; ++mf) {
        const int tl = wm * 64 + mf * 16 + lg * 4;
#pragma unroll
        for (int nf = 0; nf < 4; ++nf) {
          const int ul = nf * 16 + lr;        // 0..63 within half
          const float bb = bv[n0 + h * 64 + ul];
          s16x4 pk;
#pragma unroll
          for (int j = 0; j < 4; ++j) pk[j] = f2bf(acc[mf][nf][j] + bb);
          *(s16x4*)&lds[ul * 136 + tl] = pk;
        }
      }
    }
    __syncthreads();
#pragma unroll
    for (int it = 0; it < 4; ++it) {
      const int cid = it * 256 + tid;
      const int u = cid >> 4, tc = cid & 15;  // u:[0,64) tc:[0,16)
      s16x8 v8 = *(const s16x8*)&lds[u * 136 + tc * 8];
      *(s16x8*)(VT + ((size_t)b * 1024 + n0 + h * 64 + u) * 2048 + t0 + tc * 8) = v8;
    }
    __syncthreads();
  }
}

// ==== QK^T: scores=(Q.K)/32; 128x128 tile, grid 1024 (4 bt x 16 bm x 16 bn) ====
__global__ __launch_bounds__(256, 3) void qkt_kernel(const short* __restrict__ Qb,
                                                     const short* __restrict__ Kb,
                                                     short* __restrict__ Sb) {
  __shared__ short lds[8192];
  const int o = xswz(blockIdx.x, 1024);
  const int bt = o >> 8, r = o & 255;
  const int bm = r >> 4, bn = r & 15;         // [0,16) each
  const short* A = Qb + (size_t)bt * 2097152;
  const short* B = Kb + (size_t)bt * 2097152;
  short* O = Sb + (size_t)bt * 4194304;
  const int m0 = bm * 128, n0 = bn * 128;
  f32x4 acc[4][4];
#pragma unroll
  for (int i = 0; i < 4; ++i)
#pragma unroll
    for (int j = 0; j < 4; ++j) acc[i][j] = (f32x4){0.f, 0.f, 0.f, 0.f};
  gemm97_core(A, B, 1024, 1024, m0, n0, 32, lds, acc);
  const int l = threadIdx.x & 63, w = threadIdx.x >> 6;
  const int wm = w >> 1, wn = w & 1, lr = l & 15, lg = l >> 4;
#pragma unroll
  for (int mf = 0; mf < 4; ++mf) {
    const int row0 = m0 + wm * 64 + mf * 16 + lg * 4;  // <= 2047
#pragma unroll
    for (int nf = 0; nf < 4; ++nf) {
      const int col = n0 + wn * 64 + nf * 16 + lr;     // <= 2047
#pragma unroll
      for (int j = 0; j < 4; ++j)
        O[(size_t)(row0 + j) * 2048 + col] = f2bf(acc[mf][nf][j] * 0.03125f);
    }
  }
}

// ==== PV: out = P @ V (VT layout); 128x128 tile, grid 512 (4 bt x 16 bm x 8 bn) ====
__global__ __launch_bounds__(256, 3) void pv_kernel(const short* __restrict__ Sb,
                                                    const short* __restrict__ VT,
                                                    float* __restrict__ Out) {
  __shared__ short lds[8192];
  const int o = xswz(blockIdx.x, 512);
  const int bt = o >> 7, r = o & 127;
  const int bm = r >> 3, bn = r & 7;          // bm:[0,16) bn:[0,8)
  const short* A = Sb + (size_t)bt * 4194304;
  const short* B = VT + (size_t)bt * 2097152;
  float* O = Out + (size_t)bt * 2097152;
  const int m0 = bm * 128, n0 = bn * 128;
  f32x4 acc[4][4];
#pragma unroll
  for (int i = 0; i < 4; ++i)
#pragma unroll
    for (int j = 0; j < 4; ++j) acc[i][j] = (f32x4){0.f, 0.f, 0.f, 0.f};
  gemm97_core(A, B, 2048, 2048, m0, n0, 64, lds, acc);
  const int l = threadIdx.x & 63, w = threadIdx.x >> 6;
  const int wm = w >> 1, wn = w & 1, lr = l & 15, lg = l >> 4;
#pragma unroll
  for (int mf = 0; mf < 4; ++mf) {
    const int row0 = m0 + wm * 64 + mf * 16 + lg * 4;  // <= 2047
#pragma unroll
    for (int nf = 0; nf < 4; ++nf) {
      const int col = n0 + wn * 64 + nf * 16 + lr;     // <= 1023
#pragma unroll
      for (int j = 0; j < 4; ++j)
        O[(size_t)(row0 + j) * 1024 + col] = acc[mf][nf][j];
    }
  }
}

// ============ Row softmax, in-place on bf16 scores [B*S rows][2048] ============
__global__ __launch_bounds__(256) void softmax_kernel(short* __restrict__ Sb) {
  const size_t row = blockIdx.x;
  short* p = Sb + row * 2048;
  const int tid = threadIdx.x;
  const int w = tid >> 6, l = tid & 63;
  s16x8 v = *(const s16x8*)(p + tid * 8);
  float f[8];
#pragma unroll
  for (int j = 0; j < 8; ++j) f[j] = bf2f(v[j]);
  float m = f[0];
#pragma unroll
  for (int j = 1; j < 8; ++j) m = fmaxf(m, f[j]);
#pragma unroll
  for (int o = 32; o > 0; o >>= 1) m = fmaxf(m, __shfl_xor(m, o, 64));
  __shared__ float redm[4], reds[4];
  if (l == 0) redm[w] = m;
  __syncthreads();
  m = fmaxf(fmaxf(redm[0], redm[1]), fmaxf(redm[2], redm[3]));
  float s = 0.f;
#pragma unroll
  for (int j = 0; j < 8; ++j) { f[j] = __expf(f[j] - m); s += f[j]; }
#pragma unroll
  for (int o = 32; o > 0; o >>= 1) s += __shfl_xor(s, o, 64);
  if (l == 0) reds[w] = s;
  __syncthreads();
  s = reds[0] + reds[1] + reds[2] + reds[3];
  const float inv = 1.f / s;
  s16x8 o8;
#pragma unroll
  for (int j = 0; j < 8; ++j) o8[j] = f2bf(f[j] * inv);
  *(s16x8*)(p + tid * 8) = o8;
}

// ============ launch ============
extern "C" void kernel_launch(void* const* d_in, const int* in_sizes, int n_in,
                              void* d_out, int out_size, void* d_ws, size_t ws_size,
                              hipStream_t stream) {
  const float* query = (const float*)d_in[0];
  const float* value = (const float*)d_in[1];
  const float* Wq = (const float*)d_in[2];
  const float* bq = (const float*)d_in[3];
  const float* Wk = (const float*)d_in[4];
  const float* bk = (const float*)d_in[5];
  const float* Wv = (const float*)d_in[6];
  const float* bv = (const float*)d_in[7];

  // Workspace layout (86 MB total):
  //  0: WTq(2M) 2M: WTk(2M) 4M: WTv(2M)
  //  6M: region X (32MB): Qc@6M(16M), Vc@22M(16M); later Sb@6M(32MB) [disjoint lifetimes]
  //  38M: Qb(16M) 54M: Kb(16M) 70M: VT(16M)
  char* ws = (char*)d_ws;
  short* WTq = (short*)(ws);
  short* WTk = (short*)(ws + ((size_t)2 << 20));
  short* WTv = (short*)(ws + ((size_t)4 << 20));
  short* Qc  = (short*)(ws + ((size_t)6 << 20));
  short* Vc  = (short*)(ws + ((size_t)22 << 20));
  short* Sb  = (short*)(ws + ((size_t)6 << 20));
  short* Qb  = (short*)(ws + ((size_t)38 << 20));
  short* Kb  = (short*)(ws + ((size_t)54 << 20));
  short* VT  = (short*)(ws + ((size_t)70 << 20));

  prep_kernel<<<dim3(8960), 256, 0, stream>>>(query, value, Wq, Wk, Wv, Qc, Vc, WTq, WTk, WTv);

  qkproj_kernel<<<dim3(1024), 256, 0, stream>>>(Qc, Vc, WTq, WTk, bq, bk, Qb, Kb);
  vproj_kernel<<<dim3(512), 256, 0, stream>>>(Vc, WTv, bv, VT);

  // scores[b][s][t] = (Q.K)/32
  qkt_kernel<<<dim3(1024), 256, 0, stream>>>(Qb, Kb, Sb);

  softmax_kernel<<<dim3(8192), 256, 0, stream>>>(Sb);

  // out[b][s][u] = P @ V
  pv_kernel<<<dim3(512), 256, 0, stream>>>(Sb, VT, (float*)d_out);
}